// Round 27
// baseline (660.233 us; speedup 1.0000x reference)
//
#include <hip/hip_runtime.h>
#include <hip/hip_bf16.h>
#include <math.h>

#define NTOK 36864   // tokens per batch (192*192)
#define NTOT 73728   // total tokens (B=2)
#define CDIM 192
#define C3   576
#define NH   6
#define HD   32
#define RD   20
#define NTD  128     // dictionary tokens
#define GSZ  128     // ac-msa group size
#define NGRP 288     // groups per batch
#define MLP  384
#define TDF  48
#define CH   432     // MLP+TDF
#define RAWLD 384    // concat(win, aca) raw stride
#define TDO_LD 260   // fused td-side output stride: [kn(20) | vtd(192) | tdf(48)]

typedef __hip_bfloat16 bf16;
typedef __attribute__((ext_vector_type(8))) short short8;
typedef __attribute__((ext_vector_type(4))) float f32x4;

// fast GELU (tanh form); validated absmax-neutral in rounds 13-26.
__device__ __forceinline__ float gelu_f(float x) {
    float u = x * (1.5957691216f + 0.0713548162f * x * x);
    return x / (1.0f + __expf(-u));
}

__device__ __forceinline__ unsigned short f32_to_bf16u(float f) {
    unsigned int u = __float_as_uint(f);
    u = (u + 0x7FFFu + ((u >> 16) & 1u)) >> 16;   // RNE
    return (unsigned short)u;
}

// truncating bf16 pair pack (3 ops); validated absmax-neutral in rounds 16-26.
__device__ __forceinline__ unsigned pack2bf(float a, float b) {
    return (__float_as_uint(a) >> 16) | (__float_as_uint(b) & 0xFFFF0000u);
}

__device__ __forceinline__ float bfbits2f(unsigned short u) {
    return __uint_as_float(((unsigned)u) << 16);
}

#define PACKW_TOT (192*576 + 192*192*2 + 192*384 + 432*192 + 192*16 + 192*TDO_LD)
#define HISTZ_TOT (576 * NTD)

// ---------------- LN1 (f32+bf16 out) fused with weight pack + hist zero ------
__global__ void ln1_packw_kernel(
        const float* __restrict__ x, const float* __restrict__ g,
        const float* __restrict__ be, float* __restrict__ outf,
        bf16* __restrict__ outh,
        const float* __restrict__ wqkv, const float* __restrict__ wproj,
        const float* __restrict__ aproj, const float* __restrict__ w1,
        const float* __restrict__ w2,
        const float* __restrict__ awk, const float* __restrict__ awv,
        const float* __restrict__ fcw,
        bf16* __restrict__ wqkvT, bf16* __restrict__ projT,
        bf16* __restrict__ w1T, bf16* __restrict__ w2T,
        float* __restrict__ wcomb, int* __restrict__ hist) {
    if (blockIdx.x < NTOT / 4) {
        long tok = (long)blockIdx.x * 4 + (threadIdx.x >> 6);
        int lane = threadIdx.x & 63;
        const float* row = x + tok * CDIM;
        float v0 = row[lane], v1 = row[lane + 64], v2 = row[lane + 128];
        float s  = v0 + v1 + v2;
        float ss = v0 * v0 + v1 * v1 + v2 * v2;
        #pragma unroll
        for (int o = 32; o > 0; o >>= 1) {
            s  += __shfl_down(s, o);
            ss += __shfl_down(ss, o);
        }
        s = __shfl(s, 0); ss = __shfl(ss, 0);
        float mean = s * (1.0f / 192.0f);
        float var  = ss * (1.0f / 192.0f) - mean * mean;
        float rstd = rsqrtf(var + 1e-5f);
        float r0 = (v0 - mean) * rstd * g[lane]       + be[lane];
        float r1 = (v1 - mean) * rstd * g[lane + 64]  + be[lane + 64];
        float r2 = (v2 - mean) * rstd * g[lane + 128] + be[lane + 128];
        float* orow = outf + tok * CDIM;
        orow[lane] = r0; orow[lane + 64] = r1; orow[lane + 128] = r2;
        bf16* hrow = outh + tok * CDIM;
        hrow[lane]       = __float2bfloat16(r0);
        hrow[lane + 64]  = __float2bfloat16(r1);
        hrow[lane + 128] = __float2bfloat16(r2);
        return;
    }
    int i = (blockIdx.x - NTOT / 4) * 256 + threadIdx.x;
    const int S0 = 192 * 576, S1 = 192 * 192, S2 = 192 * 192, S3 = 192 * 384,
              S4 = 432 * 192, S5 = 192 * 16, S6 = 192 * TDO_LD, S7 = HISTZ_TOT;
    if (i < S0) { int k = i / 576, n = i % 576; wqkvT[(long)n * 192 + k] = __float2bfloat16(wqkv[i]); return; }
    i -= S0;
    if (i < S1) { int k = i / 192, n = i % 192; projT[(long)n * 384 + k] = __float2bfloat16(wproj[i]); return; }
    i -= S1;
    if (i < S2) { int k = i / 192, n = i % 192; projT[(long)n * 384 + 192 + k] = __float2bfloat16(aproj[i]); return; }
    i -= S2;
    if (i < S3) { int k = i / 384, n = i % 384; w1T[(long)n * 192 + k] = __float2bfloat16(w1[i]); return; }
    i -= S3;
    if (i < S4) { int k = i / 192, n = i % 192; w2T[(long)n * 448 + k] = __float2bfloat16(w2[i]); return; }
    i -= S4;
    if (i < S5) { int n = i / 16, k = i % 16; w2T[(long)n * 448 + 432 + k] = __float2bfloat16(0.0f); return; }
    i -= S5;
    if (i < S6) {
        int k = i / TDO_LD, n = i % TDO_LD;
        float v;
        if (n < RD)            v = awk[k * RD + n];
        else if (n < RD + 192) v = awv[k * 192 + (n - RD)];
        else                   v = fcw[k * TDF + (n - RD - 192)];
        wcomb[(long)k * TDO_LD + n] = v;
        return;
    }
    i -= S6;
    if (i < S7) hist[i] = 0;
}

// ---------------- LayerNorm (bf16-only variant for LN2) ----------------------
__global__ void ln2_kernel(const float* __restrict__ x, const float* __restrict__ g,
                           const float* __restrict__ be, bf16* __restrict__ outh) {
    long tok = (long)blockIdx.x * 4 + (threadIdx.x >> 6);
    int lane = threadIdx.x & 63;
    const float* row = x + tok * CDIM;
    float v0 = row[lane], v1 = row[lane + 64], v2 = row[lane + 128];
    float s  = v0 + v1 + v2;
    float ss = v0 * v0 + v1 * v1 + v2 * v2;
    #pragma unroll
    for (int o = 32; o > 0; o >>= 1) {
        s  += __shfl_down(s, o);
        ss += __shfl_down(ss, o);
    }
    s = __shfl(s, 0); ss = __shfl(ss, 0);
    float mean = s * (1.0f / 192.0f);
    float var  = ss * (1.0f / 192.0f) - mean * mean;
    float rstd = rsqrtf(var + 1e-5f);
    float r0 = (v0 - mean) * rstd * g[lane]       + be[lane];
    float r1 = (v1 - mean) * rstd * g[lane + 64]  + be[lane + 64];
    float r2 = (v2 - mean) * rstd * g[lane + 128] + be[lane + 128];
    bf16* hrow = outh + tok * CDIM;
    hrow[lane]       = __float2bfloat16(r0);
    hrow[lane + 64]  = __float2bfloat16(r1);
    hrow[lane + 128] = __float2bfloat16(r2);
}

// ---------------- bf16 MFMA GEMM, pre-transposed bf16 B ----------------------
// 128x64 tile, 4 waves 2x2, BK=64 (round-12 proven config). Optional batch
// dim via blockIdx.z with element strides sA/sB/sC.
#define LDT 72   // padded stride in bf16 units (144 B)
template<int ACC, int GELU, int BF16OUT, int CHUNK8, int ADDX, int PL8OUT = 0>
__global__ void __launch_bounds__(256) gemm_bt(
        const bf16* __restrict__ A, const bf16* __restrict__ Bt,
        void* __restrict__ Cv, const float* __restrict__ Xadd,
        int M, int N, int K, int lda, int ldbt, int ldc,
        long sA, long sB, long sC) {
    long bz = blockIdx.z;
    A  += bz * sA;
    Bt += bz * sB;
    if (BF16OUT) Cv = (void*)((bf16*)Cv + bz * sC);
    else         Cv = (void*)((float*)Cv + bz * sC);
    if (ADDX) Xadd += bz * sC;

    __shared__ short As[128 * LDT];
    __shared__ short Bs[64 * LDT];
    int tid  = threadIdx.x;
    int lane = tid & 63;
    int w    = tid >> 6;
    int wr = w >> 1, wc = w & 1;
    int row0 = blockIdx.y * 128, col0 = blockIdx.x * 64;
    int fr = lane & 15, fq = lane >> 4;
    f32x4 acc[4][2];
    #pragma unroll
    for (int m = 0; m < 4; ++m)
        #pragma unroll
        for (int n = 0; n < 2; ++n) acc[m][n] = (f32x4)(0.0f);

    int sa_row = tid >> 3;          // 0..31
    int sa_kc  = (tid & 7) * 8;     // 0..56
    int sb_col = tid & 63;
    int sb_kb  = (tid >> 6) * 16;   // 0,16,32,48
    bool cok = (col0 + sb_col) < N;

    for (int k0 = 0; k0 < K; k0 += 64) {
        __syncthreads();
        int kk = k0 + sa_kc;
        #pragma unroll
        for (int p = 0; p < 4; ++p) {
            int r = sa_row + p * 32;
            short8 v = (short8)(0);
            if (kk + 8 <= K) {
                const bf16* src;
                if (CHUNK8)
                    src = A + ((long)(kk >> 3) * NTOT + row0 + r) * 8;
                else
                    src = A + (long)(row0 + r) * lda + kk;
                v = *(const short8*)src;
            } else if (!CHUNK8 && kk < K) {
                #pragma unroll
                for (int i = 0; i < 8; ++i)
                    v[i] = (kk + i < K) ? *(const short*)&A[(long)(row0 + r) * lda + kk + i]
                                        : (short)0;
            }
            *(short8*)&As[r * LDT + sa_kc] = v;
        }
        {
            short8 v0 = (short8)(0), v1 = (short8)(0);
            if (cok) {
                const bf16* src = Bt + (long)(col0 + sb_col) * ldbt + k0 + sb_kb;
                v0 = *(const short8*)src;
                v1 = *(const short8*)(src + 8);
            }
            *(short8*)&Bs[sb_col * LDT + sb_kb]     = v0;
            *(short8*)&Bs[sb_col * LDT + sb_kb + 8] = v1;
        }
        __syncthreads();
        short8 af[4][2], bf_[2][2];
        #pragma unroll
        for (int m = 0; m < 4; ++m) {
            int r = wr * 64 + m * 16 + fr;
            af[m][0] = *(const short8*)&As[r * LDT + fq * 8];
            af[m][1] = *(const short8*)&As[r * LDT + 32 + fq * 8];
        }
        #pragma unroll
        for (int n = 0; n < 2; ++n) {
            int c = wc * 32 + n * 16 + fr;
            bf_[n][0] = *(const short8*)&Bs[c * LDT + fq * 8];
            bf_[n][1] = *(const short8*)&Bs[c * LDT + 32 + fq * 8];
        }
        #pragma unroll
        for (int m = 0; m < 4; ++m)
            #pragma unroll
            for (int n = 0; n < 2; ++n) {
                acc[m][n] = __builtin_amdgcn_mfma_f32_16x16x32_bf16(
                                af[m][0], bf_[n][0], acc[m][n], 0, 0, 0);
                acc[m][n] = __builtin_amdgcn_mfma_f32_16x16x32_bf16(
                                af[m][1], bf_[n][1], acc[m][n], 0, 0, 0);
            }
    }
    #pragma unroll
    for (int m = 0; m < 4; ++m) {
        #pragma unroll
        for (int n = 0; n < 2; ++n) {
            int gc = col0 + wc * 32 + n * 16 + fr;
            if (gc >= N) continue;
            #pragma unroll
            for (int r = 0; r < 4; ++r) {
                int gr = row0 + wr * 64 + m * 16 + fq * 4 + r;
                float vv = acc[m][n][r];
                if (GELU) vv = gelu_f(vv);
                if (BF16OUT) {
                    long o;
                    if (PL8OUT) o = ((long)(gc >> 3) * NTOT + gr) * 8 + (gc & 7);
                    else        o = (long)gr * ldc + gc;
                    ((bf16*)Cv)[o] = __float2bfloat16(vv);
                } else {
                    long o = (long)gr * ldc + gc;
                    float* Cc = (float*)Cv;
                    if (ADDX) Cc[o] = Xadd[o] + vv;
                    else if (ACC) Cc[o] += vv;
                    else Cc[o] = vv;
                }
            }
        }
    }
}

// ---------------- Generic tiled f32 GEMM (fused td-side matrix) --------------
// TDPACK: epilogue additionally writes the bf16 transposed vtdT/tdfT slices.
template<int ACC, int GELU, int TDPACK>
__global__ void __launch_bounds__(256) gemm_kernel(
        const float* __restrict__ A, const float* __restrict__ B,
        float* __restrict__ Cc, int M, int N, int K, int lda, int ldb, int ldc,
        bf16* __restrict__ vtdT, bf16* __restrict__ tdfT) {
    __shared__ float As[16][68];
    __shared__ float Bs[16][68];
    int tid = threadIdx.x;
    int tr = tid >> 4, tc = tid & 15;
    int row0 = blockIdx.y * 64, col0 = blockIdx.x * 64;
    float acc[4][4] = {};
    int lm = tid >> 4;
    int lk = tid & 15;
    int bk = tid >> 6;
    int bn = tid & 63;
    for (int k0 = 0; k0 < K; k0 += 16) {
        #pragma unroll
        for (int i = 0; i < 4; ++i) {
            int m = lm + i * 16;
            int gr = row0 + m;
            As[lk][m] = (gr < M) ? A[(long)gr * lda + (k0 + lk)] : 0.0f;
        }
        #pragma unroll
        for (int i = 0; i < 4; ++i) {
            int kk = bk + i * 4;
            int gc = col0 + bn;
            Bs[kk][bn] = (gc < N) ? B[(long)(k0 + kk) * ldb + gc] : 0.0f;
        }
        __syncthreads();
        #pragma unroll
        for (int kk = 0; kk < 16; ++kk) {
            float4 av = *(const float4*)&As[kk][tr * 4];
            float4 bv = *(const float4*)&Bs[kk][tc * 4];
            float a[4] = {av.x, av.y, av.z, av.w};
            float b[4] = {bv.x, bv.y, bv.z, bv.w};
            #pragma unroll
            for (int i = 0; i < 4; ++i)
                #pragma unroll
                for (int j = 0; j < 4; ++j)
                    acc[i][j] = fmaf(a[i], b[j], acc[i][j]);
        }
        __syncthreads();
    }
    #pragma unroll
    for (int i = 0; i < 4; ++i) {
        int gr = row0 + tr * 4 + i;
        if (gr >= M) continue;
        #pragma unroll
        for (int j = 0; j < 4; ++j) {
            int gc = col0 + tc * 4 + j;
            if (gc >= N) continue;
            float v = acc[i][j];
            if (GELU) v = gelu_f(v);
            long o = (long)gr * ldc + gc;
            if (ACC) Cc[o] += v; else Cc[o] = v;
            if (TDPACK && gc >= RD) {
                bf16 hv = __float2bfloat16(v);
                int bb = gr >> 7;          // batch (M = 2*NTD = 256)
                int kk2 = gr & (NTD - 1);  // dict row
                if (gc < RD + CDIM)
                    vtdT[(long)bb * CDIM * NTD + (long)(gc - RD) * NTD + kk2] = hv;
                else
                    tdfT[(long)bb * TDF * NTD + (long)(gc - RD - CDIM) * NTD + kk2] = hv;
            }
        }
    }
}

// ---------------- qn = l2norm(xn @ awq) : block = 256 tokens -----------------
__global__ void __launch_bounds__(256) qn_kernel(
        const float* __restrict__ xn, const float* __restrict__ awq,
        float* __restrict__ qn) {
    __shared__ float aw[192 * RD];     // 15.4 KB
    __shared__ float xs[256 * 33];     // 33.8 KB
    int tid = threadIdx.x;
    long tok0 = (long)blockIdx.x * 256;
    for (int e = tid; e < 192 * RD; e += 256) aw[e] = awq[e];
    float acc[RD];
    #pragma unroll
    for (int j = 0; j < RD; ++j) acc[j] = 0.0f;
    for (int kc = 0; kc < 192; kc += 32) {
        __syncthreads();
        for (int e = tid; e < 256 * 32; e += 256) {
            int tk = e >> 5, kk = e & 31;
            xs[tk * 33 + kk] = xn[(tok0 + tk) * CDIM + kc + kk];
        }
        __syncthreads();
        #pragma unroll 8
        for (int kk = 0; kk < 32; ++kk) {
            float v = xs[tid * 33 + kk];
            const float* ar = &aw[(kc + kk) * RD];
            #pragma unroll
            for (int j = 0; j < RD; ++j) acc[j] = fmaf(v, ar[j], acc[j]);
        }
    }
    float ss = 0.0f;
    #pragma unroll
    for (int j = 0; j < RD; ++j) ss += acc[j] * acc[j];
    float inv = 1.0f / fmaxf(sqrtf(ss), 1e-12f);
    float* orow = qn + (tok0 + tid) * RD;
    #pragma unroll
    for (int j = 0; j < RD; ++j) orow[j] = acc[j] * inv;
}

// ---------------- ATD sim softmax + argmax + atomic histogram ----------------
__global__ void __launch_bounds__(256) sim_kernel(
        const float* __restrict__ qn, const float* __restrict__ kn,
        const float* __restrict__ scale_p, bf16* __restrict__ sim,
        int* __restrict__ tkid, int* __restrict__ hist) {
    int lane = threadIdx.x & 63;
    long tok = (long)blockIdx.x * 4 + (threadIdx.x >> 6);
    int b = (tok >= NTOK) ? 1 : 0;
    float q[RD];
    const float* qrow = qn + tok * RD;
    #pragma unroll
    for (int r = 0; r < RD; ++r) q[r] = qrow[r];
    const float* k0 = kn + ((long)b * NTD + lane) * TDO_LD;
    const float* k1 = k0 + (long)64 * TDO_LD;
    float k0v[RD], k1v[RD];
    #pragma unroll
    for (int r = 0; r < RD; ++r) { k0v[r] = k0[r]; k1v[r] = k1[r]; }
    float ss0 = 0.0f, ss1 = 0.0f;
    #pragma unroll
    for (int r = 0; r < RD; ++r) {
        ss0 += k0v[r] * k0v[r];
        ss1 += k1v[r] * k1v[r];
    }
    float inv0 = 1.0f / fmaxf(sqrtf(ss0), 1e-12f);
    float inv1 = 1.0f / fmaxf(sqrtf(ss1), 1e-12f);
    float s0 = 0.0f, s1 = 0.0f;
    #pragma unroll
    for (int r = 0; r < RD; ++r) {
        s0 = fmaf(q[r], k0v[r] * inv0, s0);
        s1 = fmaf(q[r], k1v[r] * inv1, s1);
    }
    float scl = 1.0f + fminf(fmaxf(scale_p[0], 0.0f), 3.0f) * logf(128.0f);
    s0 *= scl; s1 *= scl;
    float m; int mi;
    if (s0 >= s1) { m = s0; mi = lane; } else { m = s1; mi = lane + 64; }
    #pragma unroll
    for (int o = 1; o < 64; o <<= 1) {
        float om = __shfl_xor(m, o);
        int   oi = __shfl_xor(mi, o);
        if (om > m || (om == m && oi < mi)) { m = om; mi = oi; }
    }
    float p0 = __expf(s0 - m), p1 = __expf(s1 - m);
    float t = p0 + p1;
    #pragma unroll
    for (int o = 1; o < 64; o <<= 1) t += __shfl_xor(t, o);
    float inv = 1.0f / t;
    bf16* srow = sim + tok * NTD;
    srow[lane]      = __float2bfloat16(p0 * inv);
    srow[lane + 64] = __float2bfloat16(p1 * inv);
    if (lane == 0) {
        tkid[tok] = mi;
        atomicAdd(&hist[(tok >> 7) * NTD + mi], 1);
    }
}

// ---------------- stable counting sort: scan1 / scatter ----------------------
__global__ void __launch_bounds__(64) scan1_kernel(int* __restrict__ hist,
                                                   int* __restrict__ tot) {
    int bc = blockIdx.x;            // b*NTD + c
    int b = bc >> 7, c = bc & (NTD - 1);
    int lane = threadIdx.x;
    if (lane < 32) {
        int base = (b * NGRP + lane * 9) * NTD + c;
        int v[9];
        int s = 0;
        #pragma unroll
        for (int k = 0; k < 9; ++k) { v[k] = hist[base + k * NTD]; s += v[k]; }
        int run = s;
        #pragma unroll
        for (int o = 1; o < 32; o <<= 1) {
            int t = __shfl_up(run, o);
            if (lane >= o) run += t;
        }
        if (lane == 31) tot[bc] = run;
        int acc = run - s;
        #pragma unroll
        for (int k = 0; k < 9; ++k) { hist[base + k * NTD] = acc; acc += v[k]; }
    }
}

// scatter with the cross-category scan (old scan2) recomputed per block in LDS
__global__ void __launch_bounds__(128) scatter_kernel(const int* __restrict__ tkid,
                                                      const int* __restrict__ hist,
                                                      const int* __restrict__ tot,
                                                      int* __restrict__ idxs) {
    int tile = blockIdx.x;
    int b = tile / NGRP;
    int gl = tile % NGRP;
    int tid = threadIdx.x;
    __shared__ int cats[GSZ];
    __shared__ int basec[NTD];
    __shared__ int wsum[2];
    {
        int lane = tid & 63, wv = tid >> 6;
        int s = tot[b * NTD + tid];
        int run = s;
        #pragma unroll
        for (int o = 1; o < 64; o <<= 1) {
            int t = __shfl_up(run, o);
            if (lane >= o) run += t;
        }
        if (lane == 63) wsum[wv] = run;
        __syncthreads();
        int add = (wv == 1) ? wsum[0] : 0;
        basec[tid] = run - s + add;
    }
    int cat = tkid[tile * GSZ + tid];
    cats[tid] = cat;
    __syncthreads();
    int rank = 0;
    for (int j = 0; j < tid; ++j) rank += (cats[j] == cat) ? 1 : 0;
    int pos = hist[tile * NTD + cat] + basec[cat] + rank;
    idxs[b * NTOK + pos] = gl * GSZ + tid;
}

#define VLDW 264  // win V^T stride (528 B)
#define VLDA 136  // aca V^T stride (272 B)

// ===== O^T attention core: S^T = mfma(K_frag, Q_frag) -> lane-local softmax
// (no-max; shift-invariant, |s| small) -> P^T exchange -> O^T = mfma(V^T,P^T).
// MERGED kernel (r26): blocks [0,1728) = window attention; blocks
// [1728,3456) = TWO ac-msa pairs per block. r27: win V-staging writes
// reordered (ii = (i+2*ch)&7) to kill the 4-way bank conflict — the set of
// (addr,value) pairs per thread is unchanged, LDS content bit-identical.
#define WIN_BLOCKS (288 * NH)
__global__ void __launch_bounds__(256) attn_mfma(
        const bf16* __restrict__ qkv, const float* __restrict__ rpb,
        const int* __restrict__ idxs, bf16* __restrict__ raw) {
    __shared__ __align__(16) char smem[41280];
    int tid = threadIdx.x;

    if (blockIdx.x < WIN_BLOCKS) {
        // ---------------- window attention path ----------------
        short* Kt = (short*)smem;                         // 256*40*2 = 20480
        short* Vt = (short*)(smem + 20480);               // 32*264*2 = 16896
        float* rb = (float*)(smem + 20480 + 16896);       // 961*4    =  3844
        int t2  = blockIdx.x;
        int h   = t2 % NH;
        int wid = t2 / NH;
        int b = wid / 144;
        int wrem = wid % 144;
        int wy = wrem / 12, wx = wrem % 12;
        long base_tok = (long)b * NTOK;

        int lane = tid & 63;
        int wv = tid >> 6;
        int fr = lane & 15, fq = lane >> 4;
        const float scl = 0.17677669529663687f;

        for (int i = tid; i < 961; i += 256) rb[i] = rpb[i * NH + h];

        short8 qf[4];
        #pragma unroll
        for (int m = 0; m < 4; ++m) {
            int q = wv * 64 + m * 16 + fr;
            long nq = base_tok + (long)(wy * 16 + (q >> 4)) * 192 + (wx * 16 + (q & 15));
            qf[m] = *(const short8*)(qkv + nq * C3 + h * HD + fq * 8);
        }

        {
            int s_ = tid >> 2, ch = tid & 3;
            #pragma unroll
            for (int t = 0; t < 4; ++t) {
                int p = t * 64 + s_;
                long nk = base_tok + (long)(wy * 16 + (p >> 4)) * 192 + (wx * 16 + (p & 15));
                const bf16* kb = qkv + nk * C3 + CDIM + h * HD + ch * 8;
                *(short8*)&Kt[p * 40 + ch * 8] = *(const short8*)kb;
                short8 vv = *(const short8*)(kb + CDIM);
                // bank-conflict-free write order: quad lanes (ch=0..3) hit
                // rows (i+2ch)&7 -> banks 8 apart instead of identical.
                #pragma unroll
                for (int i = 0; i < 8; ++i) {
                    int ii = (i + ch * 2) & 7;
                    Vt[(ch * 8 + ii) * VLDW + p] = vv[ii];
                }
            }
        }
        __syncthreads();

        f32x4 acc[4][2];
        float lst[4];
        #pragma unroll
        for (int m = 0; m < 4; ++m) {
            acc[m][0] = (f32x4)(0.0f); acc[m][1] = (f32x4)(0.0f);
            lst[m] = 0.0f;
        }

        for (int t = 0; t < 4; ++t) {
            short8 ak[4], av[2][2];
            #pragma unroll
            for (int c = 0; c < 4; ++c)
                ak[c] = *(const short8*)&Kt[(t * 64 + c * 16 + fr) * 40 + fq * 8];
            #pragma unroll
            for (int n = 0; n < 2; ++n)
                #pragma unroll
                for (int ks = 0; ks < 2; ++ks)
                    av[n][ks] = *(const short8*)&Vt[(n * 16 + fr) * VLDW + t * 64 + ks * 32 + fq * 8];

            #pragma unroll
            for (int m = 0; m < 4; ++m) {
                int q = wv * 64 + m * 16 + fr;
                int iy = q >> 4, ix = q & 15;
                int bxb = ix + 15 - 4 * fq;
                float s[4][4];
                #pragma unroll
                for (int c = 0; c < 4; ++c) {
                    f32x4 s4 = (f32x4)(0.0f);
                    s4 = __builtin_amdgcn_mfma_f32_16x16x32_bf16(ak[c], qf[m], s4, 0, 0, 0);
                    const float* rbp = &rb[(iy + 15 - (t * 4 + c)) * 31 + bxb];
                    #pragma unroll
                    for (int r = 0; r < 4; ++r)
                        s[c][r] = s4[r] * scl + rbp[-r];
                }
                float ps = 0.0f;
                #pragma unroll
                for (int c = 0; c < 4; ++c)
                    #pragma unroll
                    for (int r = 0; r < 4; ++r) {
                        float p = __expf(s[c][r]);
                        s[c][r] = p;
                        ps += p;
                    }
                ps += __shfl_xor(ps, 16);
                ps += __shfl_xor(ps, 32);
                lst[m] += ps;
                unsigned pk[4][2];
                #pragma unroll
                for (int c = 0; c < 4; ++c) {
                    pk[c][0] = pack2bf(s[c][0], s[c][1]);
                    pk[c][1] = pack2bf(s[c][2], s[c][3]);
                }
                #pragma unroll
                for (int ks = 0; ks < 2; ++ks) {
                    unsigned u[4];
                    #pragma unroll
                    for (int jj = 0; jj < 4; ++jj) {
                        int src = fr + 16 * (2 * (fq & 1) + (jj >> 1));
                        unsigned lo = (unsigned)__shfl((int)pk[2 * ks][jj & 1], src);
                        unsigned hi = (unsigned)__shfl((int)pk[2 * ks + 1][jj & 1], src);
                        u[jj] = (fq & 2) ? hi : lo;
                    }
                    short8 pb;
                    #pragma unroll
                    for (int jj = 0; jj < 4; ++jj) {
                        pb[2 * jj]     = (short)(u[jj] & 0xFFFF);
                        pb[2 * jj + 1] = (short)(u[jj] >> 16);
                    }
                    #pragma unroll
                    for (int n = 0; n < 2; ++n)
                        acc[m][n] = __builtin_amdgcn_mfma_f32_16x16x32_bf16(
                                        av[n][ks], pb, acc[m][n], 0, 0, 0);
                }
            }
        }
        #pragma unroll
        for (int m = 0; m < 4; ++m) {
            int q = wv * 64 + m * 16 + fr;
            long nq = base_tok + (long)(wy * 16 + (q >> 4)) * 192 + (wx * 16 + (q & 15));
            float inv = 1.0f / lst[m];
            #pragma unroll
            for (int n = 0; n < 2; ++n) {
                uint2 wv2;
                wv2.x = pack2bf(acc[m][n][0] * inv, acc[m][n][1] * inv);
                wv2.y = pack2bf(acc[m][n][2] * inv, acc[m][n][3] * inv);
                *(uint2*)(raw + nq * RAWLD + h * HD + n * 16 + 4 * fq) = wv2;
            }
        }
        return;
    }

    // ---------------- AC-MSA path: two (grp,head) pairs per block ------------
    int sub  = tid >> 7;         // 0 or 1: which pair
    int tidl = tid & 127;        // local tid within the pair
    int t2   = (blockIdx.x - WIN_BLOCKS) * 2 + sub;   // 0..3455
    short* Kt = (short*)(smem + sub * 19456);                 // 128*40*2 = 10240
    short* Vt = (short*)(smem + sub * 19456 + 10240);         // 32*136*2 =  8704
    int* sidx = (int*)  (smem + sub * 19456 + 10240 + 8704);  // 128*4    =   512
    int h    = t2 % NH;
    int grp  = t2 / NH;
    int b = grp / NGRP;
    int g = grp % NGRP;
    long btok = (long)b * NTOK;

    int lane = tidl & 63;
    int half = tidl >> 6;
    int fr = lane & 15, fq = lane >> 4;
    const float scl = 0.17677669529663687f;

    sidx[tidl] = idxs[btok + g * GSZ + tidl];
    __syncthreads();

    short8 qf[4];
    #pragma unroll
    for (int m = 0; m < 4; ++m) {
        long n = btok + sidx[half * 64 + m * 16 + fr];
        qf[m] = *(const short8*)(qkv + n * C3 + h * HD + fq * 8);
    }

    {
        int s_ = tidl >> 1, hf = tidl & 1;
        int d0 = hf * 16;
        #pragma unroll
        for (int t = 0; t < 2; ++t) {
            int p = t * 64 + s_;
            long n = btok + sidx[p];
            const bf16* kb = qkv + n * C3 + CDIM + h * HD + d0;
            *(short8*)&Kt[p * 40 + d0]     = *(const short8*)kb;
            *(short8*)&Kt[p * 40 + d0 + 8] = *(const short8*)(kb + 8);
            short8 v0 = *(const short8*)(kb + CDIM);
            short8 v1 = *(const short8*)(kb + CDIM + 8);
            #pragma unroll
            for (int i = 0; i < 8; ++i) {
                Vt[(d0 + i) * VLDA + p]     = v0[i];
                Vt[(d0 + 8 + i) * VLDA + p] = v1[i];
            }
        }
    }
    __syncthreads();

    f32x4 acc[4][2];
    float lst[4];
    #pragma unroll
    for (int m = 0; m < 4; ++m) {
        acc[m][0] = (f32x4)(0.0f); acc[m][1] = (f32x4)(0.0f);
        lst[m] = 0.0f;
    }

    for (int t = 0; t < 2; ++t) {
        short8 ak[4], av[2][2];
        #pragma unroll
        for (int c = 0; c < 4; ++c)
            ak[c] = *(const short8*)&Kt[(t * 64 + c * 16 + fr) * 40 + fq * 8];
        #pragma unroll
        for (int n = 0; n < 2; ++n)
            #pragma unroll
            for (int ks = 0; ks < 2; ++ks)
                av[n][ks] = *(const short8*)&Vt[(n * 16 + fr) * VLDA + t * 64 + ks * 32 + fq * 8];

        #pragma unroll
        for (int m = 0; m < 4; ++m) {
            float s[4][4];
            #pragma unroll
            for (int c = 0; c < 4; ++c) {
                f32x4 s4 = (f32x4)(0.0f);
                s4 = __builtin_amdgcn_mfma_f32_16x16x32_bf16(ak[c], qf[m], s4, 0, 0, 0);
                #pragma unroll
                for (int r = 0; r < 4; ++r) s[c][r] = s4[r] * scl;
            }
            float ps = 0.0f;
            #pragma unroll
            for (int c = 0; c < 4; ++c)
                #pragma unroll
                for (int r = 0; r < 4; ++r) {
                    float p = __expf(s[c][r]);
                    s[c][r] = p;
                    ps += p;
                }
            ps += __shfl_xor(ps, 16);
            ps += __shfl_xor(ps, 32);
            lst[m] += ps;
            unsigned pk[4][2];
            #pragma unroll
            for (int c = 0; c < 4; ++c) {
                pk[c][0] = pack2bf(s[c][0], s[c][1]);
                pk[c][1] = pack2bf(s[c][2], s[c][3]);
            }
            #pragma unroll
            for (int ks = 0; ks < 2; ++ks) {
                unsigned u[4];
                #pragma unroll
                for (int jj = 0; jj < 4; ++jj) {
                    int src = fr + 16 * (2 * (fq & 1) + (jj >> 1));
                    unsigned lo = (unsigned)__shfl((int)pk[2 * ks][jj & 1], src);
                    unsigned hi = (unsigned)__shfl((int)pk[2 * ks + 1][jj & 1], src);
                    u[jj] = (fq & 2) ? hi : lo;
                }
                short8 pb;
                #pragma unroll
                for (int jj = 0; jj < 4; ++jj) {
                    pb[2 * jj]     = (short)(u[jj] & 0xFFFF);
                    pb[2 * jj + 1] = (short)(u[jj] >> 16);
                }
                #pragma unroll
                for (int n = 0; n < 2; ++n)
                    acc[m][n] = __builtin_amdgcn_mfma_f32_16x16x32_bf16(
                                    av[n][ks], pb, acc[m][n], 0, 0, 0);
            }
        }
    }
    #pragma unroll
    for (int m = 0; m < 4; ++m) {
        long n = btok + sidx[half * 64 + m * 16 + fr];
        float inv = 1.0f / lst[m];
        #pragma unroll
        for (int nn = 0; nn < 2; ++nn) {
            uint2 wv2;
            wv2.x = pack2bf(acc[m][nn][0] * inv, acc[m][nn][1] * inv);
            wv2.y = pack2bf(acc[m][nn][2] * inv, acc[m][nn][3] * inv);
            *(uint2*)(raw + n * RAWLD + CDIM + h * HD + nn * 16 + 4 * fq) = wv2;
        }
    }
}

// ---------------- depthwise 5x5 conv + gelu + residual -----------------------
// f32 LDS staging, register w[25], 32x32 tile, 4 px/thread (round-17 proven).
#define CPS 1296   // ys plane stride (36*36 floats)
__global__ void __launch_bounds__(256) conv_kernel(
        const bf16* __restrict__ y, const float* __restrict__ dw,
        bf16* __restrict__ zc) {
    int bid = blockIdx.x;
    int ck   = bid % 54;
    int tile = (bid / 54) % 36;
    int b    = bid / (54 * 36);
    int ty = tile / 6, tx = tile % 6;
    int c0 = ck * 8;
    __shared__ float ys[8 * CPS];   // 41.5 KB
    __shared__ float wt[8 * 25];
    int tid = threadIdx.x;
    const bf16* ypl = y + ((long)ck * NTOT + (long)b * NTOK) * 8;
    for (int p = tid; p < 1296; p += 256) {
        int ly = p / 36, lx = p - ly * 36;
        int gy = ty * 32 + ly - 2, gx = tx * 32 + lx - 2;
        float f[8];
        if (gy >= 0 && gy < 192 && gx >= 0 && gx < 192) {
            short8 hv = *(const short8*)(ypl + (long)(gy * 192 + gx) * 8);
            #pragma unroll
            for (int i = 0; i < 8; ++i) f[i] = bfbits2f((unsigned short)hv[i]);
        } else {
            #pragma unroll
            for (int i = 0; i < 8; ++i) f[i] = 0.0f;
        }
        #pragma unroll
        for (int i = 0; i < 8; ++i) ys[i * CPS + p] = f[i];
    }
    for (int e = tid; e < 200; e += 256) wt[e] = dw[c0 * 25 + e];
    __syncthreads();
    int col = tid & 31, r4 = tid >> 5;
    int py0 = r4 * 4;
    long tok0 = (long)b * NTOK + (long)(ty * 32 + py0) * 192 + tx * 32 + col;
    unsigned hh[4][4];
    for (int c = 0; c < 8; ++c) {
        const float* yc = &ys[c * CPS];
        float w[25];
        #pragma unroll
        for (int t = 0; t < 25; ++t) w[t] = wt[c * 25 + t];
        float a[4] = {0.0f, 0.0f, 0.0f, 0.0f};
        #pragma unroll
        for (int dy2 = 0; dy2 < 8; ++dy2) {
            float rv[5];
            #pragma unroll
            for (int dx = 0; dx < 5; ++dx)
                rv[dx] = yc[(py0 + dy2) * 36 + col + dx];
            #pragma unroll
            for (int i = 0; i < 4; ++i) {
                int dy = dy2 - i;
                if (dy >= 0 && dy < 5) {
                    #pragma unroll
                    for (int dx = 0; dx < 5; ++dx)
                        a[i] = fmaf(rv[dx], w[dy * 5 + dx], a[i]);
                }
            }
        }
        #pragma unroll
        for (int i = 0; i < 4; ++i) {
            float center = yc[(py0 + i + 2) * 36 + col + 2];
            unsigned short hsh = f32_to_bf16u(center + gelu_f(a[i]));
            if (c & 1) hh[i][c >> 1] |= ((unsigned)hsh) << 16;
            else       hh[i][c >> 1] = (unsigned)hsh;
        }
    }
    #pragma unroll
    for (int i = 0; i < 4; ++i) {
        long tok = tok0 + (long)i * 192;
        *(uint4*)(zc + ((long)ck * NTOT + tok) * 8) =
            make_uint4(hh[i][0], hh[i][1], hh[i][2], hh[i][3]);
    }
}

// =============================================================================
extern "C" void kernel_launch(void* const* d_in, const int* in_sizes, int n_in,
                              void* d_out, int out_size, void* d_ws, size_t ws_size,
                              hipStream_t stream) {
    (void)in_sizes; (void)n_in; (void)out_size; (void)ws_size;
    const float* x     = (const float*)d_in[0];
    const float* td    = (const float*)d_in[1];
    const float* n1g   = (const float*)d_in[2];
    const float* n1b   = (const float*)d_in[3];
    const float* n2g   = (const float*)d_in[4];
    const float* n2b   = (const float*)d_in[5];
    const float* wqkv  = (const float*)d_in[6];
    const float* rpb   = (const float*)d_in[7];
    const float* wproj = (const float*)d_in[8];
    const float* awq   = (const float*)d_in[9];
    const float* awk   = (const float*)d_in[10];
    const float* awv   = (const float*)d_in[11];
    const float* ascl  = (const float*)d_in[12];
    const float* aproj = (const float*)d_in[13];
    const float* fcw   = (const float*)d_in[14];
    const float* w1    = (const float*)d_in[15];
    const float* dw    = (const float*)d_in[16];
    const float* w2    = (const float*)d_in[17];
    float* out = (float*)d_out;

    char* ws = (char*)d_ws;
    size_t off = 0;
    auto alloc = [&](size_t bytes) -> char* {
        char* p = ws + off;
        off += (bytes + 255) & ~(size_t)255;
        return p;
    };
    bf16*  qkv  = (bf16*)alloc((size_t)NTOT * C3 * 2);       // R0: qkv -> y (planar)
    float* xn   = (float*)alloc((size_t)NTOT * CDIM * 4);    // R1: xn f32 -> raw bf16 -> zc head
    bf16*  xnh  = (bf16*)alloc((size_t)NTOT * CDIM * 2);     // R2: LN bf16 -> zc tail
    float* qn   = (float*)alloc((size_t)NTOT * RD * 4);
    bf16*  simb = (bf16*)alloc((size_t)NTOT * NTD * 2);
    float* tdo  = (float*)alloc((size_t)2 * NTD * TDO_LD * 4);  // [kn|vtd|tdf]
    float* wcomb= (float*)alloc((size_t)192 * TDO_LD * 4);
    bf16*  vtdT = (bf16*)alloc((size_t)2 * CDIM * NTD * 2);
    bf16*  tdfT = (bf16*)alloc((size_t)2 * TDF * NTD * 2);
    bf16*  wqkvT= (bf16*)alloc((size_t)C3 * CDIM * 2);
    bf16*  projT= (bf16*)alloc((size_t)CDIM * 384 * 2);
    bf16*  w1T  = (bf16*)alloc((size_t)MLP * CDIM * 2);
    bf16*  w2T  = (bf16*)alloc((size_t)CDIM * 448 * 2);
    int*   tkid = (int*)alloc((size_t)NTOT * 4);
    int*   idxs = (int*)alloc((size_t)NTOT * 4);
    int*   hist = (int*)alloc((size_t)576 * NTD * 4);
    int*   tot  = (int*)alloc((size_t)2 * NTD * 4);
    bf16*  y    = qkv;          // reuse R0 (planar [54][NTOT][8])
    bf16*  raw  = (bf16*)xn;    // reuse R1
    bf16*  zc   = (bf16*)xn;    // chunk-planar z spans R1 + part of R2

    // LN1 (f32 + bf16) fused with weight pack + hist zeroing: one launch
    ln1_packw_kernel<<<NTOT / 4 + (PACKW_TOT + HISTZ_TOT + 255) / 256, 256, 0, stream>>>(
        x, n1g, n1b, xn, xnh,
        wqkv, wproj, aproj, w1, w2, awk, awv, fcw,
        wqkvT, projT, w1T, w2T, wcomb, hist);

    // qkv (bf16) = xnh @ wqkv
    gemm_bt<0,0,1,0,0><<<dim3(9, 576), 256, 0, stream>>>(
        xnh, wqkvT, qkv, nullptr, NTOT, C3, CDIM, CDIM, CDIM, C3, 0, 0, 0);

    // qn = l2norm(xn @ awq)   (f32 discrete path)
    qn_kernel<<<NTOT / 256, 256, 0, stream>>>(xn, awq, qn);

    // td-side: ONE fused f32 gemm; epilogue emits bf16 vtdT/tdfT directly
    gemm_kernel<0,0,1><<<dim3(5, 4), 256, 0, stream>>>(
        td, wcomb, tdo, 2 * NTD, TDO_LD, CDIM, CDIM, TDO_LD, TDO_LD, vtdT, tdfT);

    // sim = softmax(qn @ l2n(kn)^T * scale), tkid = argmax, hist via atomics
    sim_kernel<<<NTOT / 4, 256, 0, stream>>>(qn, tdo, ascl, simb, tkid, hist);

    // out = x + sim @ vtd (fused residual, batched grid.z=2)
    gemm_bt<0,0,0,0,1><<<dim3(3, 288, 2), 256, 0, stream>>>(
        simb, vtdT, out, x, NTOK, CDIM, NTD, NTD, NTD, CDIM,
        (long)NTOK * NTD, (long)CDIM * NTD, (long)NTOK * CDIM);

    // stable counting sort: scan1 + scatter w/ inline scan2 (hist from sim)
    scan1_kernel<<<2 * NTD, 64, 0, stream>>>(hist, tot);
    scatter_kernel<<<576, 128, 0, stream>>>(tkid, hist, tot, idxs);

    // MERGED attention (win + 2x aca per block) -> raw, then fused projection
    attn_mfma<<<WIN_BLOCKS + (576 * NH) / 2, 256, 0, stream>>>(qkv, rpb, idxs, raw);
    gemm_bt<1,0,0,0,0><<<dim3(3, 576), 256, 0, stream>>>(
        raw, projT, out, nullptr, NTOT, CDIM, 384, RAWLD, 384, CDIM, 0, 0, 0);

    // x_td = sim @ tdf written DIRECTLY planar into y planes 48..53 (PL8OUT).
    // Must run after attention (qkv dead): this region aliases live qkv data.
    gemm_bt<0,0,1,0,0,1><<<dim3(1, 288, 2), 256, 0, stream>>>(
        simb, tdfT, y + (long)48 * NTOT * 8, nullptr, NTOK, TDF, NTD, NTD, NTD, 0,
        (long)NTOK * NTD, (long)TDF * NTD, (long)NTOK * 8);

    // LN2 (bf16 only); writes xnh
    ln2_kernel<<<NTOT / 4, 256, 0, stream>>>(out, n2g, n2b, xnh);

    // y planes 0..47 = gelu(xnh @ w1) (planar out)
    gemm_bt<0,1,1,0,0,1><<<dim3(6, 576), 256, 0, stream>>>(
        xnh, w1T, y, nullptr, NTOT, MLP, CDIM, CDIM, CDIM, 0, 0, 0, 0);

    // zc = y + gelu(dwconv5x5(y)) (planar in/out), then out += zc @ w2 (K=432)
    conv_kernel<<<2 * 36 * 54, 256, 0, stream>>>(y, dw, zc);
    gemm_bt<1,0,0,1,0><<<dim3(3, 576), 256, 0, stream>>>(
        zc, w2T, out, nullptr, NTOT, CDIM, CH, 0, 448, CDIM, 0, 0, 0);
}

// Round 28
// 654.765 us; speedup vs baseline: 1.0084x; 1.0084x over previous
//
#include <hip/hip_runtime.h>
#include <hip/hip_bf16.h>
#include <math.h>

#define NTOK 36864   // tokens per batch (192*192)
#define NTOT 73728   // total tokens (B=2)
#define CDIM 192
#define C3   576
#define NH   6
#define HD   32
#define RD   20
#define NTD  128     // dictionary tokens
#define GSZ  128     // ac-msa group size
#define NGRP 288     // groups per batch
#define MLP  384
#define TDF  48
#define CH   432     // MLP+TDF
#define RAWLD 384    // concat(win, aca) raw stride
#define TDO_LD 260   // fused td-side output stride: [kn(20) | vtd(192) | tdf(48)]

typedef __hip_bfloat16 bf16;
typedef __attribute__((ext_vector_type(8))) short short8;
typedef __attribute__((ext_vector_type(4))) float f32x4;

// fast GELU (tanh form); validated absmax-neutral in rounds 13-27.
__device__ __forceinline__ float gelu_f(float x) {
    float u = x * (1.5957691216f + 0.0713548162f * x * x);
    return x / (1.0f + __expf(-u));
}

__device__ __forceinline__ unsigned short f32_to_bf16u(float f) {
    unsigned int u = __float_as_uint(f);
    u = (u + 0x7FFFu + ((u >> 16) & 1u)) >> 16;   // RNE
    return (unsigned short)u;
}

// truncating bf16 pair pack (3 ops); validated absmax-neutral in rounds 16-27.
__device__ __forceinline__ unsigned pack2bf(float a, float b) {
    return (__float_as_uint(a) >> 16) | (__float_as_uint(b) & 0xFFFF0000u);
}

__device__ __forceinline__ float bfbits2f(unsigned short u) {
    return __uint_as_float(((unsigned)u) << 16);
}

#define PACKW_TOT (192*576 + 192*192*2 + 192*384 + 432*192 + 192*16 + 192*TDO_LD)
#define HISTZ_TOT (576 * NTD)

// ---------------- LN1 (f32+bf16 out) fused with weight pack + hist zero ------
__global__ void ln1_packw_kernel(
        const float* __restrict__ x, const float* __restrict__ g,
        const float* __restrict__ be, float* __restrict__ outf,
        bf16* __restrict__ outh,
        const float* __restrict__ wqkv, const float* __restrict__ wproj,
        const float* __restrict__ aproj, const float* __restrict__ w1,
        const float* __restrict__ w2,
        const float* __restrict__ awk, const float* __restrict__ awv,
        const float* __restrict__ fcw,
        bf16* __restrict__ wqkvT, bf16* __restrict__ projT,
        bf16* __restrict__ w1T, bf16* __restrict__ w2T,
        float* __restrict__ wcomb, int* __restrict__ hist) {
    if (blockIdx.x < NTOT / 4) {
        long tok = (long)blockIdx.x * 4 + (threadIdx.x >> 6);
        int lane = threadIdx.x & 63;
        const float* row = x + tok * CDIM;
        float v0 = row[lane], v1 = row[lane + 64], v2 = row[lane + 128];
        float s  = v0 + v1 + v2;
        float ss = v0 * v0 + v1 * v1 + v2 * v2;
        #pragma unroll
        for (int o = 32; o > 0; o >>= 1) {
            s  += __shfl_down(s, o);
            ss += __shfl_down(ss, o);
        }
        s = __shfl(s, 0); ss = __shfl(ss, 0);
        float mean = s * (1.0f / 192.0f);
        float var  = ss * (1.0f / 192.0f) - mean * mean;
        float rstd = rsqrtf(var + 1e-5f);
        float r0 = (v0 - mean) * rstd * g[lane]       + be[lane];
        float r1 = (v1 - mean) * rstd * g[lane + 64]  + be[lane + 64];
        float r2 = (v2 - mean) * rstd * g[lane + 128] + be[lane + 128];
        float* orow = outf + tok * CDIM;
        orow[lane] = r0; orow[lane + 64] = r1; orow[lane + 128] = r2;
        bf16* hrow = outh + tok * CDIM;
        hrow[lane]       = __float2bfloat16(r0);
        hrow[lane + 64]  = __float2bfloat16(r1);
        hrow[lane + 128] = __float2bfloat16(r2);
        return;
    }
    int i = (blockIdx.x - NTOT / 4) * 256 + threadIdx.x;
    const int S0 = 192 * 576, S1 = 192 * 192, S2 = 192 * 192, S3 = 192 * 384,
              S4 = 432 * 192, S5 = 192 * 16, S6 = 192 * TDO_LD, S7 = HISTZ_TOT;
    if (i < S0) { int k = i / 576, n = i % 576; wqkvT[(long)n * 192 + k] = __float2bfloat16(wqkv[i]); return; }
    i -= S0;
    if (i < S1) { int k = i / 192, n = i % 192; projT[(long)n * 384 + k] = __float2bfloat16(wproj[i]); return; }
    i -= S1;
    if (i < S2) { int k = i / 192, n = i % 192; projT[(long)n * 384 + 192 + k] = __float2bfloat16(aproj[i]); return; }
    i -= S2;
    if (i < S3) { int k = i / 384, n = i % 384; w1T[(long)n * 192 + k] = __float2bfloat16(w1[i]); return; }
    i -= S3;
    if (i < S4) { int k = i / 192, n = i % 192; w2T[(long)n * 448 + k] = __float2bfloat16(w2[i]); return; }
    i -= S4;
    if (i < S5) { int n = i / 16, k = i % 16; w2T[(long)n * 448 + 432 + k] = __float2bfloat16(0.0f); return; }
    i -= S5;
    if (i < S6) {
        int k = i / TDO_LD, n = i % TDO_LD;
        float v;
        if (n < RD)            v = awk[k * RD + n];
        else if (n < RD + 192) v = awv[k * 192 + (n - RD)];
        else                   v = fcw[k * TDF + (n - RD - 192)];
        wcomb[(long)k * TDO_LD + n] = v;
        return;
    }
    i -= S6;
    if (i < S7) hist[i] = 0;
}

// ---------------- LayerNorm (bf16-only variant for LN2) ----------------------
__global__ void ln2_kernel(const float* __restrict__ x, const float* __restrict__ g,
                           const float* __restrict__ be, bf16* __restrict__ outh) {
    long tok = (long)blockIdx.x * 4 + (threadIdx.x >> 6);
    int lane = threadIdx.x & 63;
    const float* row = x + tok * CDIM;
    float v0 = row[lane], v1 = row[lane + 64], v2 = row[lane + 128];
    float s  = v0 + v1 + v2;
    float ss = v0 * v0 + v1 * v1 + v2 * v2;
    #pragma unroll
    for (int o = 32; o > 0; o >>= 1) {
        s  += __shfl_down(s, o);
        ss += __shfl_down(ss, o);
    }
    s = __shfl(s, 0); ss = __shfl(ss, 0);
    float mean = s * (1.0f / 192.0f);
    float var  = ss * (1.0f / 192.0f) - mean * mean;
    float rstd = rsqrtf(var + 1e-5f);
    float r0 = (v0 - mean) * rstd * g[lane]       + be[lane];
    float r1 = (v1 - mean) * rstd * g[lane + 64]  + be[lane + 64];
    float r2 = (v2 - mean) * rstd * g[lane + 128] + be[lane + 128];
    bf16* hrow = outh + tok * CDIM;
    hrow[lane]       = __float2bfloat16(r0);
    hrow[lane + 64]  = __float2bfloat16(r1);
    hrow[lane + 128] = __float2bfloat16(r2);
}

// ---------------- bf16 MFMA GEMM, pre-transposed bf16 B ----------------------
// 128x64 tile, 4 waves 2x2, BK=64 (round-12 proven config). Optional batch
// dim via blockIdx.z with element strides sA/sB/sC.
#define LDT 72   // padded stride in bf16 units (144 B)
template<int ACC, int GELU, int BF16OUT, int CHUNK8, int ADDX, int PL8OUT = 0>
__global__ void __launch_bounds__(256) gemm_bt(
        const bf16* __restrict__ A, const bf16* __restrict__ Bt,
        void* __restrict__ Cv, const float* __restrict__ Xadd,
        int M, int N, int K, int lda, int ldbt, int ldc,
        long sA, long sB, long sC) {
    long bz = blockIdx.z;
    A  += bz * sA;
    Bt += bz * sB;
    if (BF16OUT) Cv = (void*)((bf16*)Cv + bz * sC);
    else         Cv = (void*)((float*)Cv + bz * sC);
    if (ADDX) Xadd += bz * sC;

    __shared__ short As[128 * LDT];
    __shared__ short Bs[64 * LDT];
    int tid  = threadIdx.x;
    int lane = tid & 63;
    int w    = tid >> 6;
    int wr = w >> 1, wc = w & 1;
    int row0 = blockIdx.y * 128, col0 = blockIdx.x * 64;
    int fr = lane & 15, fq = lane >> 4;
    f32x4 acc[4][2];
    #pragma unroll
    for (int m = 0; m < 4; ++m)
        #pragma unroll
        for (int n = 0; n < 2; ++n) acc[m][n] = (f32x4)(0.0f);

    int sa_row = tid >> 3;          // 0..31
    int sa_kc  = (tid & 7) * 8;     // 0..56
    int sb_col = tid & 63;
    int sb_kb  = (tid >> 6) * 16;   // 0,16,32,48
    bool cok = (col0 + sb_col) < N;

    for (int k0 = 0; k0 < K; k0 += 64) {
        __syncthreads();
        int kk = k0 + sa_kc;
        #pragma unroll
        for (int p = 0; p < 4; ++p) {
            int r = sa_row + p * 32;
            short8 v = (short8)(0);
            if (kk + 8 <= K) {
                const bf16* src;
                if (CHUNK8)
                    src = A + ((long)(kk >> 3) * NTOT + row0 + r) * 8;
                else
                    src = A + (long)(row0 + r) * lda + kk;
                v = *(const short8*)src;
            } else if (!CHUNK8 && kk < K) {
                #pragma unroll
                for (int i = 0; i < 8; ++i)
                    v[i] = (kk + i < K) ? *(const short*)&A[(long)(row0 + r) * lda + kk + i]
                                        : (short)0;
            }
            *(short8*)&As[r * LDT + sa_kc] = v;
        }
        {
            short8 v0 = (short8)(0), v1 = (short8)(0);
            if (cok) {
                const bf16* src = Bt + (long)(col0 + sb_col) * ldbt + k0 + sb_kb;
                v0 = *(const short8*)src;
                v1 = *(const short8*)(src + 8);
            }
            *(short8*)&Bs[sb_col * LDT + sb_kb]     = v0;
            *(short8*)&Bs[sb_col * LDT + sb_kb + 8] = v1;
        }
        __syncthreads();
        short8 af[4][2], bf_[2][2];
        #pragma unroll
        for (int m = 0; m < 4; ++m) {
            int r = wr * 64 + m * 16 + fr;
            af[m][0] = *(const short8*)&As[r * LDT + fq * 8];
            af[m][1] = *(const short8*)&As[r * LDT + 32 + fq * 8];
        }
        #pragma unroll
        for (int n = 0; n < 2; ++n) {
            int c = wc * 32 + n * 16 + fr;
            bf_[n][0] = *(const short8*)&Bs[c * LDT + fq * 8];
            bf_[n][1] = *(const short8*)&Bs[c * LDT + 32 + fq * 8];
        }
        #pragma unroll
        for (int m = 0; m < 4; ++m)
            #pragma unroll
            for (int n = 0; n < 2; ++n) {
                acc[m][n] = __builtin_amdgcn_mfma_f32_16x16x32_bf16(
                                af[m][0], bf_[n][0], acc[m][n], 0, 0, 0);
                acc[m][n] = __builtin_amdgcn_mfma_f32_16x16x32_bf16(
                                af[m][1], bf_[n][1], acc[m][n], 0, 0, 0);
            }
    }
    #pragma unroll
    for (int m = 0; m < 4; ++m) {
        #pragma unroll
        for (int n = 0; n < 2; ++n) {
            int gc = col0 + wc * 32 + n * 16 + fr;
            if (gc >= N) continue;
            #pragma unroll
            for (int r = 0; r < 4; ++r) {
                int gr = row0 + wr * 64 + m * 16 + fq * 4 + r;
                float vv = acc[m][n][r];
                if (GELU) vv = gelu_f(vv);
                if (BF16OUT) {
                    long o;
                    if (PL8OUT) o = ((long)(gc >> 3) * NTOT + gr) * 8 + (gc & 7);
                    else        o = (long)gr * ldc + gc;
                    ((bf16*)Cv)[o] = __float2bfloat16(vv);
                } else {
                    long o = (long)gr * ldc + gc;
                    float* Cc = (float*)Cv;
                    if (ADDX) Cc[o] = Xadd[o] + vv;
                    else if (ACC) Cc[o] += vv;
                    else Cc[o] = vv;
                }
            }
        }
    }
}

// ---------------- Generic tiled f32 GEMM (fused td-side matrix) --------------
// TDPACK: epilogue additionally writes the bf16 transposed vtdT/tdfT slices.
template<int ACC, int GELU, int TDPACK>
__global__ void __launch_bounds__(256) gemm_kernel(
        const float* __restrict__ A, const float* __restrict__ B,
        float* __restrict__ Cc, int M, int N, int K, int lda, int ldb, int ldc,
        bf16* __restrict__ vtdT, bf16* __restrict__ tdfT) {
    __shared__ float As[16][68];
    __shared__ float Bs[16][68];
    int tid = threadIdx.x;
    int tr = tid >> 4, tc = tid & 15;
    int row0 = blockIdx.y * 64, col0 = blockIdx.x * 64;
    float acc[4][4] = {};
    int lm = tid >> 4;
    int lk = tid & 15;
    int bk = tid >> 6;
    int bn = tid & 63;
    for (int k0 = 0; k0 < K; k0 += 16) {
        #pragma unroll
        for (int i = 0; i < 4; ++i) {
            int m = lm + i * 16;
            int gr = row0 + m;
            As[lk][m] = (gr < M) ? A[(long)gr * lda + (k0 + lk)] : 0.0f;
        }
        #pragma unroll
        for (int i = 0; i < 4; ++i) {
            int kk = bk + i * 4;
            int gc = col0 + bn;
            Bs[kk][bn] = (gc < N) ? B[(long)(k0 + kk) * ldb + gc] : 0.0f;
        }
        __syncthreads();
        #pragma unroll
        for (int kk = 0; kk < 16; ++kk) {
            float4 av = *(const float4*)&As[kk][tr * 4];
            float4 bv = *(const float4*)&Bs[kk][tc * 4];
            float a[4] = {av.x, av.y, av.z, av.w};
            float b[4] = {bv.x, bv.y, bv.z, bv.w};
            #pragma unroll
            for (int i = 0; i < 4; ++i)
                #pragma unroll
                for (int j = 0; j < 4; ++j)
                    acc[i][j] = fmaf(a[i], b[j], acc[i][j]);
        }
        __syncthreads();
    }
    #pragma unroll
    for (int i = 0; i < 4; ++i) {
        int gr = row0 + tr * 4 + i;
        if (gr >= M) continue;
        #pragma unroll
        for (int j = 0; j < 4; ++j) {
            int gc = col0 + tc * 4 + j;
            if (gc >= N) continue;
            float v = acc[i][j];
            if (GELU) v = gelu_f(v);
            long o = (long)gr * ldc + gc;
            if (ACC) Cc[o] += v; else Cc[o] = v;
            if (TDPACK && gc >= RD) {
                bf16 hv = __float2bfloat16(v);
                int bb = gr >> 7;          // batch (M = 2*NTD = 256)
                int kk2 = gr & (NTD - 1);  // dict row
                if (gc < RD + CDIM)
                    vtdT[(long)bb * CDIM * NTD + (long)(gc - RD) * NTD + kk2] = hv;
                else
                    tdfT[(long)bb * TDF * NTD + (long)(gc - RD - CDIM) * NTD + kk2] = hv;
            }
        }
    }
}

// ---------------- qn = l2norm(xn @ awq) : block = 256 tokens -----------------
__global__ void __launch_bounds__(256) qn_kernel(
        const float* __restrict__ xn, const float* __restrict__ awq,
        float* __restrict__ qn) {
    __shared__ float aw[192 * RD];     // 15.4 KB
    __shared__ float xs[256 * 33];     // 33.8 KB
    int tid = threadIdx.x;
    long tok0 = (long)blockIdx.x * 256;
    for (int e = tid; e < 192 * RD; e += 256) aw[e] = awq[e];
    float acc[RD];
    #pragma unroll
    for (int j = 0; j < RD; ++j) acc[j] = 0.0f;
    for (int kc = 0; kc < 192; kc += 32) {
        __syncthreads();
        for (int e = tid; e < 256 * 32; e += 256) {
            int tk = e >> 5, kk = e & 31;
            xs[tk * 33 + kk] = xn[(tok0 + tk) * CDIM + kc + kk];
        }
        __syncthreads();
        #pragma unroll 8
        for (int kk = 0; kk < 32; ++kk) {
            float v = xs[tid * 33 + kk];
            const float* ar = &aw[(kc + kk) * RD];
            #pragma unroll
            for (int j = 0; j < RD; ++j) acc[j] = fmaf(v, ar[j], acc[j]);
        }
    }
    float ss = 0.0f;
    #pragma unroll
    for (int j = 0; j < RD; ++j) ss += acc[j] * acc[j];
    float inv = 1.0f / fmaxf(sqrtf(ss), 1e-12f);
    float* orow = qn + (tok0 + tid) * RD;
    #pragma unroll
    for (int j = 0; j < RD; ++j) orow[j] = acc[j] * inv;
}

// ---------------- ATD sim softmax + argmax + atomic histogram ----------------
__global__ void __launch_bounds__(256) sim_kernel(
        const float* __restrict__ qn, const float* __restrict__ kn,
        const float* __restrict__ scale_p, bf16* __restrict__ sim,
        int* __restrict__ tkid, int* __restrict__ hist) {
    int lane = threadIdx.x & 63;
    long tok = (long)blockIdx.x * 4 + (threadIdx.x >> 6);
    int b = (tok >= NTOK) ? 1 : 0;
    float q[RD];
    const float* qrow = qn + tok * RD;
    #pragma unroll
    for (int r = 0; r < RD; ++r) q[r] = qrow[r];
    const float* k0 = kn + ((long)b * NTD + lane) * TDO_LD;
    const float* k1 = k0 + (long)64 * TDO_LD;
    float k0v[RD], k1v[RD];
    #pragma unroll
    for (int r = 0; r < RD; ++r) { k0v[r] = k0[r]; k1v[r] = k1[r]; }
    float ss0 = 0.0f, ss1 = 0.0f;
    #pragma unroll
    for (int r = 0; r < RD; ++r) {
        ss0 += k0v[r] * k0v[r];
        ss1 += k1v[r] * k1v[r];
    }
    float inv0 = 1.0f / fmaxf(sqrtf(ss0), 1e-12f);
    float inv1 = 1.0f / fmaxf(sqrtf(ss1), 1e-12f);
    float s0 = 0.0f, s1 = 0.0f;
    #pragma unroll
    for (int r = 0; r < RD; ++r) {
        s0 = fmaf(q[r], k0v[r] * inv0, s0);
        s1 = fmaf(q[r], k1v[r] * inv1, s1);
    }
    float scl = 1.0f + fminf(fmaxf(scale_p[0], 0.0f), 3.0f) * logf(128.0f);
    s0 *= scl; s1 *= scl;
    float m; int mi;
    if (s0 >= s1) { m = s0; mi = lane; } else { m = s1; mi = lane + 64; }
    #pragma unroll
    for (int o = 1; o < 64; o <<= 1) {
        float om = __shfl_xor(m, o);
        int   oi = __shfl_xor(mi, o);
        if (om > m || (om == m && oi < mi)) { m = om; mi = oi; }
    }
    float p0 = __expf(s0 - m), p1 = __expf(s1 - m);
    float t = p0 + p1;
    #pragma unroll
    for (int o = 1; o < 64; o <<= 1) t += __shfl_xor(t, o);
    float inv = 1.0f / t;
    bf16* srow = sim + tok * NTD;
    srow[lane]      = __float2bfloat16(p0 * inv);
    srow[lane + 64] = __float2bfloat16(p1 * inv);
    if (lane == 0) {
        tkid[tok] = mi;
        atomicAdd(&hist[(tok >> 7) * NTD + mi], 1);
    }
}

// ---------------- stable counting sort: scan1 / scatter ----------------------
__global__ void __launch_bounds__(64) scan1_kernel(int* __restrict__ hist,
                                                   int* __restrict__ tot) {
    int bc = blockIdx.x;            // b*NTD + c
    int b = bc >> 7, c = bc & (NTD - 1);
    int lane = threadIdx.x;
    if (lane < 32) {
        int base = (b * NGRP + lane * 9) * NTD + c;
        int v[9];
        int s = 0;
        #pragma unroll
        for (int k = 0; k < 9; ++k) { v[k] = hist[base + k * NTD]; s += v[k]; }
        int run = s;
        #pragma unroll
        for (int o = 1; o < 32; o <<= 1) {
            int t = __shfl_up(run, o);
            if (lane >= o) run += t;
        }
        if (lane == 31) tot[bc] = run;
        int acc = run - s;
        #pragma unroll
        for (int k = 0; k < 9; ++k) { hist[base + k * NTD] = acc; acc += v[k]; }
    }
}

// scatter with the cross-category scan (old scan2) recomputed per block in LDS
__global__ void __launch_bounds__(128) scatter_kernel(const int* __restrict__ tkid,
                                                      const int* __restrict__ hist,
                                                      const int* __restrict__ tot,
                                                      int* __restrict__ idxs) {
    int tile = blockIdx.x;
    int b = tile / NGRP;
    int gl = tile % NGRP;
    int tid = threadIdx.x;
    __shared__ int cats[GSZ];
    __shared__ int basec[NTD];
    __shared__ int wsum[2];
    {
        int lane = tid & 63, wv = tid >> 6;
        int s = tot[b * NTD + tid];
        int run = s;
        #pragma unroll
        for (int o = 1; o < 64; o <<= 1) {
            int t = __shfl_up(run, o);
            if (lane >= o) run += t;
        }
        if (lane == 63) wsum[wv] = run;
        __syncthreads();
        int add = (wv == 1) ? wsum[0] : 0;
        basec[tid] = run - s + add;
    }
    int cat = tkid[tile * GSZ + tid];
    cats[tid] = cat;
    __syncthreads();
    int rank = 0;
    for (int j = 0; j < tid; ++j) rank += (cats[j] == cat) ? 1 : 0;
    int pos = hist[tile * NTD + cat] + basec[cat] + rank;
    idxs[b * NTOK + pos] = gl * GSZ + tid;
}

#define VLDW 264  // win V^T stride (528 B)
#define VLDA 136  // aca V^T stride (272 B)

// ===== O^T attention core: S^T = mfma(K_frag, Q_frag) -> lane-local softmax
// (no-max; shift-invariant, |s| small) -> P^T exchange -> O^T = mfma(V^T,P^T).
// MERGED kernel: blocks [0,1728) = window attention (4 waves); blocks
// [1728,3456) = TWO ac-msa (grp,head) pairs per block (sub = tid>>7).
// One 41.3 KB LDS arena covers both paths. (r26 proven config; r27's
// V-write reorder regressed — attn is VALU/latency-bound, not LDS-bound.)
#define WIN_BLOCKS (288 * NH)
__global__ void __launch_bounds__(256) attn_mfma(
        const bf16* __restrict__ qkv, const float* __restrict__ rpb,
        const int* __restrict__ idxs, bf16* __restrict__ raw) {
    __shared__ __align__(16) char smem[41280];
    int tid = threadIdx.x;

    if (blockIdx.x < WIN_BLOCKS) {
        // ---------------- window attention path ----------------
        short* Kt = (short*)smem;                         // 256*40*2 = 20480
        short* Vt = (short*)(smem + 20480);               // 32*264*2 = 16896
        float* rb = (float*)(smem + 20480 + 16896);       // 961*4    =  3844
        int t2  = blockIdx.x;
        int h   = t2 % NH;
        int wid = t2 / NH;
        int b = wid / 144;
        int wrem = wid % 144;
        int wy = wrem / 12, wx = wrem % 12;
        long base_tok = (long)b * NTOK;

        int lane = tid & 63;
        int wv = tid >> 6;
        int fr = lane & 15, fq = lane >> 4;
        const float scl = 0.17677669529663687f;

        for (int i = tid; i < 961; i += 256) rb[i] = rpb[i * NH + h];

        short8 qf[4];
        #pragma unroll
        for (int m = 0; m < 4; ++m) {
            int q = wv * 64 + m * 16 + fr;
            long nq = base_tok + (long)(wy * 16 + (q >> 4)) * 192 + (wx * 16 + (q & 15));
            qf[m] = *(const short8*)(qkv + nq * C3 + h * HD + fq * 8);
        }

        {
            int s_ = tid >> 2, ch = tid & 3;
            #pragma unroll
            for (int t = 0; t < 4; ++t) {
                int p = t * 64 + s_;
                long nk = base_tok + (long)(wy * 16 + (p >> 4)) * 192 + (wx * 16 + (p & 15));
                const bf16* kb = qkv + nk * C3 + CDIM + h * HD + ch * 8;
                *(short8*)&Kt[p * 40 + ch * 8] = *(const short8*)kb;
                short8 vv = *(const short8*)(kb + CDIM);
                #pragma unroll
                for (int i = 0; i < 8; ++i)
                    Vt[(ch * 8 + i) * VLDW + p] = vv[i];
            }
        }
        __syncthreads();

        f32x4 acc[4][2];
        float lst[4];
        #pragma unroll
        for (int m = 0; m < 4; ++m) {
            acc[m][0] = (f32x4)(0.0f); acc[m][1] = (f32x4)(0.0f);
            lst[m] = 0.0f;
        }

        for (int t = 0; t < 4; ++t) {
            short8 ak[4], av[2][2];
            #pragma unroll
            for (int c = 0; c < 4; ++c)
                ak[c] = *(const short8*)&Kt[(t * 64 + c * 16 + fr) * 40 + fq * 8];
            #pragma unroll
            for (int n = 0; n < 2; ++n)
                #pragma unroll
                for (int ks = 0; ks < 2; ++ks)
                    av[n][ks] = *(const short8*)&Vt[(n * 16 + fr) * VLDW + t * 64 + ks * 32 + fq * 8];

            #pragma unroll
            for (int m = 0; m < 4; ++m) {
                int q = wv * 64 + m * 16 + fr;
                int iy = q >> 4, ix = q & 15;
                int bxb = ix + 15 - 4 * fq;
                float s[4][4];
                #pragma unroll
                for (int c = 0; c < 4; ++c) {
                    f32x4 s4 = (f32x4)(0.0f);
                    s4 = __builtin_amdgcn_mfma_f32_16x16x32_bf16(ak[c], qf[m], s4, 0, 0, 0);
                    const float* rbp = &rb[(iy + 15 - (t * 4 + c)) * 31 + bxb];
                    #pragma unroll
                    for (int r = 0; r < 4; ++r)
                        s[c][r] = s4[r] * scl + rbp[-r];
                }
                float ps = 0.0f;
                #pragma unroll
                for (int c = 0; c < 4; ++c)
                    #pragma unroll
                    for (int r = 0; r < 4; ++r) {
                        float p = __expf(s[c][r]);
                        s[c][r] = p;
                        ps += p;
                    }
                ps += __shfl_xor(ps, 16);
                ps += __shfl_xor(ps, 32);
                lst[m] += ps;
                unsigned pk[4][2];
                #pragma unroll
                for (int c = 0; c < 4; ++c) {
                    pk[c][0] = pack2bf(s[c][0], s[c][1]);
                    pk[c][1] = pack2bf(s[c][2], s[c][3]);
                }
                #pragma unroll
                for (int ks = 0; ks < 2; ++ks) {
                    unsigned u[4];
                    #pragma unroll
                    for (int jj = 0; jj < 4; ++jj) {
                        int src = fr + 16 * (2 * (fq & 1) + (jj >> 1));
                        unsigned lo = (unsigned)__shfl((int)pk[2 * ks][jj & 1], src);
                        unsigned hi = (unsigned)__shfl((int)pk[2 * ks + 1][jj & 1], src);
                        u[jj] = (fq & 2) ? hi : lo;
                    }
                    short8 pb;
                    #pragma unroll
                    for (int jj = 0; jj < 4; ++jj) {
                        pb[2 * jj]     = (short)(u[jj] & 0xFFFF);
                        pb[2 * jj + 1] = (short)(u[jj] >> 16);
                    }
                    #pragma unroll
                    for (int n = 0; n < 2; ++n)
                        acc[m][n] = __builtin_amdgcn_mfma_f32_16x16x32_bf16(
                                        av[n][ks], pb, acc[m][n], 0, 0, 0);
                }
            }
        }
        #pragma unroll
        for (int m = 0; m < 4; ++m) {
            int q = wv * 64 + m * 16 + fr;
            long nq = base_tok + (long)(wy * 16 + (q >> 4)) * 192 + (wx * 16 + (q & 15));
            float inv = 1.0f / lst[m];
            #pragma unroll
            for (int n = 0; n < 2; ++n) {
                uint2 wv2;
                wv2.x = pack2bf(acc[m][n][0] * inv, acc[m][n][1] * inv);
                wv2.y = pack2bf(acc[m][n][2] * inv, acc[m][n][3] * inv);
                *(uint2*)(raw + nq * RAWLD + h * HD + n * 16 + 4 * fq) = wv2;
            }
        }
        return;
    }

    // ---------------- AC-MSA path: two (grp,head) pairs per block ------------
    int sub  = tid >> 7;         // 0 or 1: which pair
    int tidl = tid & 127;        // local tid within the pair
    int t2   = (blockIdx.x - WIN_BLOCKS) * 2 + sub;   // 0..3455
    short* Kt = (short*)(smem + sub * 19456);                 // 128*40*2 = 10240
    short* Vt = (short*)(smem + sub * 19456 + 10240);         // 32*136*2 =  8704
    int* sidx = (int*)  (smem + sub * 19456 + 10240 + 8704);  // 128*4    =   512
    int h    = t2 % NH;
    int grp  = t2 / NH;
    int b = grp / NGRP;
    int g = grp % NGRP;
    long btok = (long)b * NTOK;

    int lane = tidl & 63;
    int half = tidl >> 6;
    int fr = lane & 15, fq = lane >> 4;
    const float scl = 0.17677669529663687f;

    sidx[tidl] = idxs[btok + g * GSZ + tidl];
    __syncthreads();

    short8 qf[4];
    #pragma unroll
    for (int m = 0; m < 4; ++m) {
        long n = btok + sidx[half * 64 + m * 16 + fr];
        qf[m] = *(const short8*)(qkv + n * C3 + h * HD + fq * 8);
    }

    {
        int s_ = tidl >> 1, hf = tidl & 1;
        int d0 = hf * 16;
        #pragma unroll
        for (int t = 0; t < 2; ++t) {
            int p = t * 64 + s_;
            long n = btok + sidx[p];
            const bf16* kb = qkv + n * C3 + CDIM + h * HD + d0;
            *(short8*)&Kt[p * 40 + d0]     = *(const short8*)kb;
            *(short8*)&Kt[p * 40 + d0 + 8] = *(const short8*)(kb + 8);
            short8 v0 = *(const short8*)(kb + CDIM);
            short8 v1 = *(const short8*)(kb + CDIM + 8);
            #pragma unroll
            for (int i = 0; i < 8; ++i) {
                Vt[(d0 + i) * VLDA + p]     = v0[i];
                Vt[(d0 + 8 + i) * VLDA + p] = v1[i];
            }
        }
    }
    __syncthreads();

    f32x4 acc[4][2];
    float lst[4];
    #pragma unroll
    for (int m = 0; m < 4; ++m) {
        acc[m][0] = (f32x4)(0.0f); acc[m][1] = (f32x4)(0.0f);
        lst[m] = 0.0f;
    }

    for (int t = 0; t < 2; ++t) {
        short8 ak[4], av[2][2];
        #pragma unroll
        for (int c = 0; c < 4; ++c)
            ak[c] = *(const short8*)&Kt[(t * 64 + c * 16 + fr) * 40 + fq * 8];
        #pragma unroll
        for (int n = 0; n < 2; ++n)
            #pragma unroll
            for (int ks = 0; ks < 2; ++ks)
                av[n][ks] = *(const short8*)&Vt[(n * 16 + fr) * VLDA + t * 64 + ks * 32 + fq * 8];

        #pragma unroll
        for (int m = 0; m < 4; ++m) {
            float s[4][4];
            #pragma unroll
            for (int c = 0; c < 4; ++c) {
                f32x4 s4 = (f32x4)(0.0f);
                s4 = __builtin_amdgcn_mfma_f32_16x16x32_bf16(ak[c], qf[m], s4, 0, 0, 0);
                #pragma unroll
                for (int r = 0; r < 4; ++r) s[c][r] = s4[r] * scl;
            }
            float ps = 0.0f;
            #pragma unroll
            for (int c = 0; c < 4; ++c)
                #pragma unroll
                for (int r = 0; r < 4; ++r) {
                    float p = __expf(s[c][r]);
                    s[c][r] = p;
                    ps += p;
                }
            ps += __shfl_xor(ps, 16);
            ps += __shfl_xor(ps, 32);
            lst[m] += ps;
            unsigned pk[4][2];
            #pragma unroll
            for (int c = 0; c < 4; ++c) {
                pk[c][0] = pack2bf(s[c][0], s[c][1]);
                pk[c][1] = pack2bf(s[c][2], s[c][3]);
            }
            #pragma unroll
            for (int ks = 0; ks < 2; ++ks) {
                unsigned u[4];
                #pragma unroll
                for (int jj = 0; jj < 4; ++jj) {
                    int src = fr + 16 * (2 * (fq & 1) + (jj >> 1));
                    unsigned lo = (unsigned)__shfl((int)pk[2 * ks][jj & 1], src);
                    unsigned hi = (unsigned)__shfl((int)pk[2 * ks + 1][jj & 1], src);
                    u[jj] = (fq & 2) ? hi : lo;
                }
                short8 pb;
                #pragma unroll
                for (int jj = 0; jj < 4; ++jj) {
                    pb[2 * jj]     = (short)(u[jj] & 0xFFFF);
                    pb[2 * jj + 1] = (short)(u[jj] >> 16);
                }
                #pragma unroll
                for (int n = 0; n < 2; ++n)
                    acc[m][n] = __builtin_amdgcn_mfma_f32_16x16x32_bf16(
                                    av[n][ks], pb, acc[m][n], 0, 0, 0);
            }
        }
    }
    #pragma unroll
    for (int m = 0; m < 4; ++m) {
        long n = btok + sidx[half * 64 + m * 16 + fr];
        float inv = 1.0f / lst[m];
        #pragma unroll
        for (int nn = 0; nn < 2; ++nn) {
            uint2 wv2;
            wv2.x = pack2bf(acc[m][nn][0] * inv, acc[m][nn][1] * inv);
            wv2.y = pack2bf(acc[m][nn][2] * inv, acc[m][nn][3] * inv);
            *(uint2*)(raw + n * RAWLD + CDIM + h * HD + nn * 16 + 4 * fq) = wv2;
        }
    }
}

// ---------------- depthwise 5x5 conv + gelu + residual -----------------------
// f32 LDS staging, register w[25], 32x32 tile, 4 px/thread (round-17 proven).
#define CPS 1296   // ys plane stride (36*36 floats)
__global__ void __launch_bounds__(256) conv_kernel(
        const bf16* __restrict__ y, const float* __restrict__ dw,
        bf16* __restrict__ zc) {
    int bid = blockIdx.x;
    int ck   = bid % 54;
    int tile = (bid / 54) % 36;
    int b    = bid / (54 * 36);
    int ty = tile / 6, tx = tile % 6;
    int c0 = ck * 8;
    __shared__ float ys[8 * CPS];   // 41.5 KB
    __shared__ float wt[8 * 25];
    int tid = threadIdx.x;
    const bf16* ypl = y + ((long)ck * NTOT + (long)b * NTOK) * 8;
    for (int p = tid; p < 1296; p += 256) {
        int ly = p / 36, lx = p - ly * 36;
        int gy = ty * 32 + ly - 2, gx = tx * 32 + lx - 2;
        float f[8];
        if (gy >= 0 && gy < 192 && gx >= 0 && gx < 192) {
            short8 hv = *(const short8*)(ypl + (long)(gy * 192 + gx) * 8);
            #pragma unroll
            for (int i = 0; i < 8; ++i) f[i] = bfbits2f((unsigned short)hv[i]);
        } else {
            #pragma unroll
            for (int i = 0; i < 8; ++i) f[i] = 0.0f;
        }
        #pragma unroll
        for (int i = 0; i < 8; ++i) ys[i * CPS + p] = f[i];
    }
    for (int e = tid; e < 200; e += 256) wt[e] = dw[c0 * 25 + e];
    __syncthreads();
    int col = tid & 31, r4 = tid >> 5;
    int py0 = r4 * 4;
    long tok0 = (long)b * NTOK + (long)(ty * 32 + py0) * 192 + tx * 32 + col;
    unsigned hh[4][4];
    for (int c = 0; c < 8; ++c) {
        const float* yc = &ys[c * CPS];
        float w[25];
        #pragma unroll
        for (int t = 0; t < 25; ++t) w[t] = wt[c * 25 + t];
        float a[4] = {0.0f, 0.0f, 0.0f, 0.0f};
        #pragma unroll
        for (int dy2 = 0; dy2 < 8; ++dy2) {
            float rv[5];
            #pragma unroll
            for (int dx = 0; dx < 5; ++dx)
                rv[dx] = yc[(py0 + dy2) * 36 + col + dx];
            #pragma unroll
            for (int i = 0; i < 4; ++i) {
                int dy = dy2 - i;
                if (dy >= 0 && dy < 5) {
                    #pragma unroll
                    for (int dx = 0; dx < 5; ++dx)
                        a[i] = fmaf(rv[dx], w[dy * 5 + dx], a[i]);
                }
            }
        }
        #pragma unroll
        for (int i = 0; i < 4; ++i) {
            float center = yc[(py0 + i + 2) * 36 + col + 2];
            unsigned short hsh = f32_to_bf16u(center + gelu_f(a[i]));
            if (c & 1) hh[i][c >> 1] |= ((unsigned)hsh) << 16;
            else       hh[i][c >> 1] = (unsigned)hsh;
        }
    }
    #pragma unroll
    for (int i = 0; i < 4; ++i) {
        long tok = tok0 + (long)i * 192;
        *(uint4*)(zc + ((long)ck * NTOT + tok) * 8) =
            make_uint4(hh[i][0], hh[i][1], hh[i][2], hh[i][3]);
    }
}

// =============================================================================
extern "C" void kernel_launch(void* const* d_in, const int* in_sizes, int n_in,
                              void* d_out, int out_size, void* d_ws, size_t ws_size,
                              hipStream_t stream) {
    (void)in_sizes; (void)n_in; (void)out_size; (void)ws_size;
    const float* x     = (const float*)d_in[0];
    const float* td    = (const float*)d_in[1];
    const float* n1g   = (const float*)d_in[2];
    const float* n1b   = (const float*)d_in[3];
    const float* n2g   = (const float*)d_in[4];
    const float* n2b   = (const float*)d_in[5];
    const float* wqkv  = (const float*)d_in[6];
    const float* rpb   = (const float*)d_in[7];
    const float* wproj = (const float*)d_in[8];
    const float* awq   = (const float*)d_in[9];
    const float* awk   = (const float*)d_in[10];
    const float* awv   = (const float*)d_in[11];
    const float* ascl  = (const float*)d_in[12];
    const float* aproj = (const float*)d_in[13];
    const float* fcw   = (const float*)d_in[14];
    const float* w1    = (const float*)d_in[15];
    const float* dw    = (const float*)d_in[16];
    const float* w2    = (const float*)d_in[17];
    float* out = (float*)d_out;

    char* ws = (char*)d_ws;
    size_t off = 0;
    auto alloc = [&](size_t bytes) -> char* {
        char* p = ws + off;
        off += (bytes + 255) & ~(size_t)255;
        return p;
    };
    bf16*  qkv  = (bf16*)alloc((size_t)NTOT * C3 * 2);       // R0: qkv -> y (planar)
    float* xn   = (float*)alloc((size_t)NTOT * CDIM * 4);    // R1: xn f32 -> raw bf16 -> zc head
    bf16*  xnh  = (bf16*)alloc((size_t)NTOT * CDIM * 2);     // R2: LN bf16 -> zc tail
    float* qn   = (float*)alloc((size_t)NTOT * RD * 4);
    bf16*  simb = (bf16*)alloc((size_t)NTOT * NTD * 2);
    float* tdo  = (float*)alloc((size_t)2 * NTD * TDO_LD * 4);  // [kn|vtd|tdf]
    float* wcomb= (float*)alloc((size_t)192 * TDO_LD * 4);
    bf16*  vtdT = (bf16*)alloc((size_t)2 * CDIM * NTD * 2);
    bf16*  tdfT = (bf16*)alloc((size_t)2 * TDF * NTD * 2);
    bf16*  wqkvT= (bf16*)alloc((size_t)C3 * CDIM * 2);
    bf16*  projT= (bf16*)alloc((size_t)CDIM * 384 * 2);
    bf16*  w1T  = (bf16*)alloc((size_t)MLP * CDIM * 2);
    bf16*  w2T  = (bf16*)alloc((size_t)CDIM * 448 * 2);
    int*   tkid = (int*)alloc((size_t)NTOT * 4);
    int*   idxs = (int*)alloc((size_t)NTOT * 4);
    int*   hist = (int*)alloc((size_t)576 * NTD * 4);
    int*   tot  = (int*)alloc((size_t)2 * NTD * 4);
    bf16*  y    = qkv;          // reuse R0 (planar [54][NTOT][8])
    bf16*  raw  = (bf16*)xn;    // reuse R1
    bf16*  zc   = (bf16*)xn;    // chunk-planar z spans R1 + part of R2

    // LN1 (f32 + bf16) fused with weight pack + hist zeroing: one launch
    ln1_packw_kernel<<<NTOT / 4 + (PACKW_TOT + HISTZ_TOT + 255) / 256, 256, 0, stream>>>(
        x, n1g, n1b, xn, xnh,
        wqkv, wproj, aproj, w1, w2, awk, awv, fcw,
        wqkvT, projT, w1T, w2T, wcomb, hist);

    // qkv (bf16) = xnh @ wqkv
    gemm_bt<0,0,1,0,0><<<dim3(9, 576), 256, 0, stream>>>(
        xnh, wqkvT, qkv, nullptr, NTOT, C3, CDIM, CDIM, CDIM, C3, 0, 0, 0);

    // qn = l2norm(xn @ awq)   (f32 discrete path)
    qn_kernel<<<NTOT / 256, 256, 0, stream>>>(xn, awq, qn);

    // td-side: ONE fused f32 gemm; epilogue emits bf16 vtdT/tdfT directly
    gemm_kernel<0,0,1><<<dim3(5, 4), 256, 0, stream>>>(
        td, wcomb, tdo, 2 * NTD, TDO_LD, CDIM, CDIM, TDO_LD, TDO_LD, vtdT, tdfT);

    // sim = softmax(qn @ l2n(kn)^T * scale), tkid = argmax, hist via atomics
    sim_kernel<<<NTOT / 4, 256, 0, stream>>>(qn, tdo, ascl, simb, tkid, hist);

    // out = x + sim @ vtd (fused residual, batched grid.z=2)
    gemm_bt<0,0,0,0,1><<<dim3(3, 288, 2), 256, 0, stream>>>(
        simb, vtdT, out, x, NTOK, CDIM, NTD, NTD, NTD, CDIM,
        (long)NTOK * NTD, (long)CDIM * NTD, (long)NTOK * CDIM);

    // stable counting sort: scan1 + scatter w/ inline scan2 (hist from sim)
    scan1_kernel<<<2 * NTD, 64, 0, stream>>>(hist, tot);
    scatter_kernel<<<576, 128, 0, stream>>>(tkid, hist, tot, idxs);

    // MERGED attention (win + 2x aca per block) -> raw, then fused projection
    attn_mfma<<<WIN_BLOCKS + (576 * NH) / 2, 256, 0, stream>>>(qkv, rpb, idxs, raw);
    gemm_bt<1,0,0,0,0><<<dim3(3, 576), 256, 0, stream>>>(
        raw, projT, out, nullptr, NTOT, CDIM, 384, RAWLD, 384, CDIM, 0, 0, 0);

    // x_td = sim @ tdf written DIRECTLY planar into y planes 48..53 (PL8OUT).
    // Must run after attention (qkv dead): this region aliases live qkv data.
    gemm_bt<0,0,1,0,0,1><<<dim3(1, 288, 2), 256, 0, stream>>>(
        simb, tdfT, y + (long)48 * NTOT * 8, nullptr, NTOK, TDF, NTD, NTD, NTD, 0,
        (long)NTOK * NTD, (long)TDF * NTD, (long)NTOK * 8);

    // LN2 (bf16 only); writes xnh
    ln2_kernel<<<NTOT / 4, 256, 0, stream>>>(out, n2g, n2b, xnh);

    // y planes 0..47 = gelu(xnh @ w1) (planar out)
    gemm_bt<0,1,1,0,0,1><<<dim3(6, 576), 256, 0, stream>>>(
        xnh, w1T, y, nullptr, NTOT, MLP, CDIM, CDIM, CDIM, 0, 0, 0, 0);

    // zc = y + gelu(dwconv5x5(y)) (planar in/out), then out += zc @ w2 (K=432)
    conv_kernel<<<2 * 36 * 54, 256, 0, stream>>>(y, dw, zc);
    gemm_bt<1,0,0,1,0><<<dim3(3, 576), 256, 0, stream>>>(
        zc, w2T, out, nullptr, NTOT, CDIM, CH, 0, 448, CDIM, 0, 0, 0);
}